// Round 6
// baseline (3142.396 us; speedup 1.0000x reference)
//
#include <hip/hip_runtime.h>
#include <math.h>

#define N_NODES 65536
#define NPG     4096
#define D_IN    34
#define EMB     34
#define S_DIM   4
#define P_DIM   22
#define CONCAT  78      // EMB + 2*P_DIM
#define WIDTH   126
#define KNN     8
#define HPAD    24      // padded h row (22 -> 24)
#define EPAD    36      // padded emb row (34 -> 36)
#define TILE    1024    // j-tile staged in LDS
#define NSPLIT  16      // lanes per node
#define FBIG    3.4e38f

__device__ __forceinline__ float elu1(float v) {
    return v > 0.f ? v : expm1f(v);
}

__device__ __forceinline__ bool lexlt(float da, int ja, float db, int jb) {
    return (da < db) || (da == db && ja < jb);
}

// branchless insert of (dd,jj) into sorted-desc depth-4 (slot 0 = worst kept).
// ties keep resident => lex-correct because j scans ascending per lane.
__device__ __forceinline__ void ins4(float (&d)[4], int (&ix)[4], float dd, int jj) {
    const bool s0 = dd < d[0];
    d[0] = s0 ? dd : d[0]; ix[0] = s0 ? jj : ix[0];
#pragma unroll
    for (int r = 0; r < 3; ++r) {
        const bool s = d[r] < d[r + 1];
        const float a = s ? d[r + 1] : d[r], b = s ? d[r] : d[r + 1];
        const int   x = s ? ix[r + 1] : ix[r], y = s ? ix[r] : ix[r + 1];
        d[r] = a; d[r + 1] = b; ix[r] = x; ix[r + 1] = y;
    }
}

// branchless insert into sorted-desc depth-8 (fixup path; exact for 16-way split)
__device__ __forceinline__ void ins8(float (&d)[8], int (&ix)[8], float dd, int jj) {
    const bool s0 = dd < d[0];
    d[0] = s0 ? dd : d[0]; ix[0] = s0 ? jj : ix[0];
#pragma unroll
    for (int r = 0; r < 7; ++r) {
        const bool s = d[r] < d[r + 1];
        const float a = s ? d[r + 1] : d[r], b = s ? d[r] : d[r + 1];
        const int   x = s ? ix[r + 1] : ix[r], y = s ? ix[r] : ix[r + 1];
        d[r] = a; d[r + 1] = b; ix[r] = x; ix[r + 1] = y;
    }
}

// bitonic cleaner: sort a bitonic 8-seq desc by lex (d,j)
__device__ __forceinline__ void clean8(float (&md)[8], int (&mj)[8]) {
#define CASL(i, k) { const bool sw = lexlt(md[i], mj[i], md[k], mj[k]); \
    const float a = sw ? md[k] : md[i], b = sw ? md[i] : md[k]; \
    const int   x = sw ? mj[k] : mj[i], y = sw ? mj[i] : mj[k]; \
    md[i] = a; md[k] = b; mj[i] = x; mj[k] = y; }
    CASL(0,4) CASL(1,5) CASL(2,6) CASL(3,7)
    CASL(0,2) CASL(1,3) CASL(4,6) CASL(5,7)
    CASL(0,1) CASL(2,3) CASL(4,5) CASL(6,7)
#undef CASL
}

// keep 8 lex-smallest of mine(sorted desc) + xor-m partner's, re-sorted desc
__device__ __forceinline__ void merge8(float (&md)[8], int (&mj)[8], int m) {
    float pd[8]; int pj[8];
#pragma unroll
    for (int i = 0; i < 8; ++i) { pd[i] = __shfl_xor(md[i], m); pj[i] = __shfl_xor(mj[i], m); }
#pragma unroll
    for (int i = 0; i < 8; ++i) {
        const bool lt = lexlt(md[i], mj[i], pd[7 - i], pj[7 - i]);
        const float nd = lt ? md[i] : pd[7 - i];
        const int   nj = lt ? mj[i] : pj[7 - i];
        md[i] = nd; mj[i] = nj;
    }
    clean8(md, mj);
}

// ---------------------------------------------------------------------------
// s = emb @ Ws + bs   [N,4];   h = emb @ Wh + bh   [N,22] (stored padded to 24)
// ---------------------------------------------------------------------------
__global__ __launch_bounds__(256) void sh_kernel(
        const float* __restrict__ emb, int eld,
        const float* __restrict__ Ws, const float* __restrict__ bs,
        const float* __restrict__ Wh, const float* __restrict__ bh,
        float* __restrict__ s_out, float* __restrict__ h_out) {
    __shared__ float lWs[EMB * S_DIM];
    __shared__ float lWh[EMB * P_DIM];
    __shared__ float lbs[S_DIM];
    __shared__ float lbh[P_DIM];
    for (int t = threadIdx.x; t < EMB * S_DIM; t += 256) lWs[t] = Ws[t];
    for (int t = threadIdx.x; t < EMB * P_DIM; t += 256) lWh[t] = Wh[t];
    if (threadIdx.x < S_DIM) lbs[threadIdx.x] = bs[threadIdx.x];
    if (threadIdx.x < P_DIM) lbh[threadIdx.x] = bh[threadIdx.x];
    __syncthreads();

    const int n = blockIdx.x * 256 + threadIdx.x;
    const float* __restrict__ row = emb + (size_t)n * eld;
    float e[EMB];
#pragma unroll
    for (int r = 0; r < EMB; ++r) e[r] = row[r];

    float s[S_DIM], h[P_DIM];
#pragma unroll
    for (int c = 0; c < S_DIM; ++c) s[c] = lbs[c];
#pragma unroll
    for (int c = 0; c < P_DIM; ++c) h[c] = lbh[c];
#pragma unroll
    for (int r = 0; r < EMB; ++r) {
        const float er = e[r];
#pragma unroll
        for (int c = 0; c < S_DIM; ++c) s[c] = fmaf(er, lWs[r * S_DIM + c], s[c]);
#pragma unroll
        for (int c = 0; c < P_DIM; ++c) h[c] = fmaf(er, lWh[r * P_DIM + c], h[c]);
    }
    ((float4*)s_out)[n] = make_float4(s[0], s[1], s[2], s[3]);
    float* __restrict__ hr = h_out + (size_t)n * HPAD;
#pragma unroll
    for (int c = 0; c < P_DIM; ++c) hr[c] = h[c];
}

// ---------------------------------------------------------------------------
// kNN scan: 16 lanes/node (j = ql mod 16), 2 nodes/thread share each sj read,
// branchless depth-4 lists, exact lex merge, soundness flag. Writes per-node
// top-8 (d, j-graph-local) + flag. No epilogue state -> no spill.
// grid = 2048 (16 graphs * 128 blocks, 32 nodes/block), block = 256.
// ---------------------------------------------------------------------------
__global__ __launch_bounds__(256, 4) void grav_scan(
        const float* __restrict__ s_buf,
        float* __restrict__ knnd, int* __restrict__ knnj,
        int* __restrict__ flags) {
    __shared__ float4 sl[TILE];           // 16 KB j-tile

    const int g     = blockIdx.x >> 7;
    const int chunk = blockIdx.x & 127;
    const int gbase = g * NPG;
    const int tid   = threadIdx.x;
    const int ql    = tid & 15;
    const int grp   = tid >> 4;
    const int nA    = gbase + chunk * 32 + grp * 2;
    const int nB    = nA + 1;

    const float4* __restrict__ sg = (const float4*)s_buf + gbase;
    float4 pre[4];
#pragma unroll
    for (int i = 0; i < 4; ++i) pre[i] = sg[tid + 256 * i];
    const float4 siA = ((const float4*)s_buf)[nA];
    const float4 siB = ((const float4*)s_buf)[nB];

    float dA[4], dB[4]; int jA[4], jB[4];
#pragma unroll
    for (int r = 0; r < 4; ++r) { dA[r] = FBIG; jA[r] = 0; dB[r] = FBIG; jB[r] = 0; }

#pragma unroll
    for (int i = 0; i < 4; ++i) sl[tid + 256 * i] = pre[i];
    __syncthreads();

    for (int t = 0; t < NPG / TILE; ++t) {
        if (t < NPG / TILE - 1) {
#pragma unroll
            for (int i = 0; i < 4; ++i)
                pre[i] = sg[(t + 1) * TILE + tid + 256 * i];
        }
        const int jb = t * TILE + ql;
#pragma unroll 4
        for (int k = 0; k < TILE / NSPLIT; ++k) {
            const float4 sj = sl[NSPLIT * k + ql];  // 16 distinct b128: conflict-free
            const int jj = jb + NSPLIT * k;
            {
                const float dx = siA.x - sj.x, dy = siA.y - sj.y;
                const float dz = siA.z - sj.z, dw = siA.w - sj.w;
                const float d2 = fmaf(dx, dx, fmaf(dy, dy, fmaf(dz, dz, dw * dw)));
                ins4(dA, jA, d2, jj);
            }
            {
                const float dx = siB.x - sj.x, dy = siB.y - sj.y;
                const float dz = siB.z - sj.z, dw = siB.w - sj.w;
                const float d2 = fmaf(dx, dx, fmaf(dy, dy, fmaf(dz, dz, dw * dw)));
                ins4(dB, jB, d2, jj);
            }
        }
        if (t < NPG / TILE - 1) {
            __syncthreads();
#pragma unroll
            for (int i = 0; i < 4; ++i) sl[tid + 256 * i] = pre[i];
            __syncthreads();
        }
    }

    const int lane = tid & 63;

    // ---- node A: exact merge of 16 depth-4 lists ----
    {
        float md[8]; int mj[8];
        float pd3 = __shfl_xor(dA[3], 1), pd2 = __shfl_xor(dA[2], 1);
        float pd1 = __shfl_xor(dA[1], 1), pd0 = __shfl_xor(dA[0], 1);
        int   pj3 = __shfl_xor(jA[3], 1), pj2 = __shfl_xor(jA[2], 1);
        int   pj1 = __shfl_xor(jA[1], 1), pj0 = __shfl_xor(jA[0], 1);
        md[0] = dA[0]; md[1] = dA[1]; md[2] = dA[2]; md[3] = dA[3];
        mj[0] = jA[0]; mj[1] = jA[1]; mj[2] = jA[2]; mj[3] = jA[3];
        md[4] = pd3; md[5] = pd2; md[6] = pd1; md[7] = pd0;
        mj[4] = pj3; mj[5] = pj2; mj[6] = pj1; mj[7] = pj0;
        clean8(md, mj);                       // desc+asc bitonic -> sorted desc (all 8 kept)
        merge8(md, mj, 2);
        merge8(md, mj, 4);
        merge8(md, mj, 8);

        const bool lost = !lexlt(md[0], mj[0], dA[0], jA[0]);
        const unsigned long long bal = __ballot(lost);
        const int flag = (((bal >> (lane & 48)) & 0xFFFFull) != 0ull) ? 1 : 0;

        float ds = md[0]; int js = mj[0];
#pragma unroll
        for (int r = 1; r < 8; ++r) {
            const bool p = (ql == r);
            ds = p ? md[r] : ds; js = p ? mj[r] : js;
        }
        if (ql < 8) {
            knnd[(size_t)nA * 8 + ql] = ds;
            knnj[(size_t)nA * 8 + ql] = js;
        }
        if (ql == 0) flags[nA] = flag;
    }

    // ---- node B ----
    {
        float md[8]; int mj[8];
        float pd3 = __shfl_xor(dB[3], 1), pd2 = __shfl_xor(dB[2], 1);
        float pd1 = __shfl_xor(dB[1], 1), pd0 = __shfl_xor(dB[0], 1);
        int   pj3 = __shfl_xor(jB[3], 1), pj2 = __shfl_xor(jB[2], 1);
        int   pj1 = __shfl_xor(jB[1], 1), pj0 = __shfl_xor(jB[0], 1);
        md[0] = dB[0]; md[1] = dB[1]; md[2] = dB[2]; md[3] = dB[3];
        mj[0] = jB[0]; mj[1] = jB[1]; mj[2] = jB[2]; mj[3] = jB[3];
        md[4] = pd3; md[5] = pd2; md[6] = pd1; md[7] = pd0;
        mj[4] = pj3; mj[5] = pj2; mj[6] = pj1; mj[7] = pj0;
        clean8(md, mj);
        merge8(md, mj, 2);
        merge8(md, mj, 4);
        merge8(md, mj, 8);

        const bool lost = !lexlt(md[0], mj[0], dB[0], jB[0]);
        const unsigned long long bal = __ballot(lost);
        const int flag = (((bal >> (lane & 48)) & 0xFFFFull) != 0ull) ? 1 : 0;

        float ds = md[0]; int js = mj[0];
#pragma unroll
        for (int r = 1; r < 8; ++r) {
            const bool p = (ql == r);
            ds = p ? md[r] : ds; js = p ? mj[r] : js;
        }
        if (ql < 8) {
            knnd[(size_t)nB * 8 + ql] = ds;
            knnj[(size_t)nB * 8 + ql] = js;
        }
        if (ql == 0) flags[nB] = flag;
    }
}

// ---------------------------------------------------------------------------
// Fixup: rescan flagged nodes exactly (depth-8/lane, 16-way => exact).
// grid = 128 blocks, 512 nodes/block (16 groups x 32 nodes).
// ---------------------------------------------------------------------------
__global__ __launch_bounds__(256, 4) void grav_fix(
        const float* __restrict__ s_buf,
        float* __restrict__ knnd, int* __restrict__ knnj,
        const int* __restrict__ flags) {
    const int tid = threadIdx.x;
    const int ql  = tid & 15;
    const int grp = tid >> 4;
    const int base = blockIdx.x * 512 + grp * 32;

    for (int it = 0; it < 32; ++it) {
        const int node = base + it;
        if (flags[node]) {
            const int gbase = node & ~(NPG - 1);
            const float4 si = ((const float4*)s_buf)[node];
            const float4* __restrict__ sg = (const float4*)s_buf + gbase;
            float fd[8]; int fj[8];
#pragma unroll
            for (int r = 0; r < 8; ++r) { fd[r] = FBIG; fj[r] = 0; }
            for (int k = 0; k < NPG / NSPLIT; ++k) {
                const int j = NSPLIT * k + ql;
                const float4 sj = sg[j];
                const float dx = si.x - sj.x, dy = si.y - sj.y;
                const float dz = si.z - sj.z, dw = si.w - sj.w;
                const float d2 = fmaf(dx, dx, fmaf(dy, dy, fmaf(dz, dz, dw * dw)));
                ins8(fd, fj, d2, j);
            }
            merge8(fd, fj, 1);
            merge8(fd, fj, 2);
            merge8(fd, fj, 4);
            merge8(fd, fj, 8);

            float ds = fd[0]; int js = fj[0];
#pragma unroll
            for (int r = 1; r < 8; ++r) {
                const bool p = (ql == r);
                ds = p ? fd[r] : ds; js = p ? fj[r] : js;
            }
            if (ql < 8) {
                knnd[(size_t)node * 8 + ql] = ds;
                knnj[(size_t)node * 8 + ql] = js;
            }
        }
    }
}

// ---------------------------------------------------------------------------
// Gather + aggregate + fused output GEMM. 64 nodes/block, 4 lanes/node.
// Phase 1: chunk-wise (float4) weighted mean/max of the 8 neighbors -> LDS.
// Phase 2: out[n] = [emb | mean | max] @ Wo + bo.
// ---------------------------------------------------------------------------
template <int ELD, bool TOUT>
__global__ __launch_bounds__(256, 4) void grav_gather(
        const float* __restrict__ emb_in,
        const float* __restrict__ h_buf,
        const float* __restrict__ knnd, const int* __restrict__ knnj,
        const float* __restrict__ Wo, const float* __restrict__ bo,
        float* __restrict__ out) {
    __shared__ float wot[EMB * 81];       // Wo^T, rows padded 78 -> 81
    __shared__ float bol[EMB];
    __shared__ float cc[64][49];          // per-node mean[0..21] @0, max[0..21] @24

    const int tid = threadIdx.x;
    const int q   = tid & 3;
    const int nl  = tid >> 2;
    const int node = blockIdx.x * 64 + nl;
    const int gbase = node & ~(NPG - 1);

    for (int t = tid; t < CONCAT * EMB; t += 256) {
        const int r = t / EMB, c = t % EMB;
        wot[c * 81 + r] = Wo[t];
    }
    if (tid < EMB) bol[tid] = bo[tid];

    // ---- phase 1: two neighbors per lane, chunked aggregation ----
    const float da = knnd[(size_t)node * 8 + q];
    const float db = knnd[(size_t)node * 8 + 4 + q];
    const int   ja = knnj[(size_t)node * 8 + q];
    const int   jb = knnj[(size_t)node * 8 + 4 + q];
    const float wa = expf(-10.f * da);
    const float wb = expf(-10.f * db);
    const float4* __restrict__ ha = (const float4*)(h_buf + (size_t)(gbase + ja) * HPAD);
    const float4* __restrict__ hb = (const float4*)(h_buf + (size_t)(gbase + jb) * HPAD);

#pragma unroll
    for (int ch = 0; ch < 6; ++ch) {
        const float4 qa = ha[ch], qb = hb[ch];
        float sx = fmaf(wa, qa.x, wb * qb.x), sy = fmaf(wa, qa.y, wb * qb.y);
        float sz = fmaf(wa, qa.z, wb * qb.z), sw = fmaf(wa, qa.w, wb * qb.w);
        float mx = fmaxf(wa * qa.x, wb * qb.x), my = fmaxf(wa * qa.y, wb * qb.y);
        float mz = fmaxf(wa * qa.z, wb * qb.z), mw = fmaxf(wa * qa.w, wb * qb.w);
#pragma unroll
        for (int m = 1; m <= 2; m <<= 1) {
            sx += __shfl_xor(sx, m); sy += __shfl_xor(sy, m);
            sz += __shfl_xor(sz, m); sw += __shfl_xor(sw, m);
            mx = fmaxf(mx, __shfl_xor(mx, m)); my = fmaxf(my, __shfl_xor(my, m));
            mz = fmaxf(mz, __shfl_xor(mz, m)); mw = fmaxf(mw, __shfl_xor(mw, m));
        }
        if (q == (ch & 3)) {
            cc[nl][ch * 4 + 0] = sx * 0.125f; cc[nl][ch * 4 + 1] = sy * 0.125f;
            cc[nl][ch * 4 + 2] = sz * 0.125f; cc[nl][ch * 4 + 3] = sw * 0.125f;
            cc[nl][24 + ch * 4 + 0] = mx; cc[nl][24 + ch * 4 + 1] = my;
            cc[nl][24 + ch * 4 + 2] = mz; cc[nl][24 + ch * 4 + 3] = mw;
        }
    }
    __syncthreads();

    // ---- phase 2: fused output GEMM, cols c = q + 4m ----
    float e[EMB];
    const float* __restrict__ erow = emb_in + (size_t)node * ELD;
    if constexpr (ELD == 34) {
#pragma unroll
        for (int i = 0; i < 17; ++i) {
            const float2 v = ((const float2*)erow)[i];
            e[2 * i] = v.x; e[2 * i + 1] = v.y;
        }
    } else {
#pragma unroll
        for (int i = 0; i < 8; ++i) {
            const float4 v = ((const float4*)erow)[i];
            e[4 * i] = v.x; e[4 * i + 1] = v.y; e[4 * i + 2] = v.z; e[4 * i + 3] = v.w;
        }
        const float2 v = ((const float2*)erow)[16];
        e[32] = v.x; e[33] = v.y;
    }

#pragma unroll
    for (int m = 0; m < 9; ++m) {
        const int c = q + 4 * m;
        if (c < EMB) {
            const float* __restrict__ wr = &wot[c * 81];
            float acc = bol[c];
#pragma unroll
            for (int r = 0; r < EMB; ++r)   acc = fmaf(e[r], wr[r], acc);
#pragma unroll
            for (int p = 0; p < P_DIM; ++p) acc = fmaf(cc[nl][p], wr[34 + p], acc);
#pragma unroll
            for (int p = 0; p < P_DIM; ++p) acc = fmaf(cc[nl][24 + p], wr[56 + p], acc);
            if constexpr (TOUT)
                out[(size_t)c * N_NODES + node] = acc;
            else
                out[(size_t)node * EPAD + c] = acc;
        }
    }
}

// ---------------------------------------------------------------------------
// Hidden MLP layer on transposed activations: outT[c][n] = act(inT @ W + b).
// ---------------------------------------------------------------------------
template <int K, bool DOELU>
__global__ __launch_bounds__(256, 4) void mlp_t(
        const float* __restrict__ inT,    // [K][N]
        const float* __restrict__ W,      // [K][126] natural layout
        const float* __restrict__ b,      // [126]
        float* __restrict__ outT) {       // [126][N]
    __shared__ float xs[K * 64];
    const int rowbase = blockIdx.x * 64;
    for (int t = threadIdx.x; t < K * 64; t += 256) {
        const int k = t >> 6, r = t & 63;
        xs[t] = inT[(size_t)k * N_NODES + rowbase + r];
    }
    __syncthreads();

    int colbase = __builtin_amdgcn_readfirstlane(threadIdx.x >> 6) * 32;
    if (colbase > WIDTH - 32) colbase = WIDTH - 32;   // wave 3: cols 94..125
    const int lane = threadIdx.x & 63;
    const int row  = rowbase + lane;

    float acc[32];
#pragma unroll
    for (int o = 0; o < 32; ++o) acc[o] = b[colbase + o];

#pragma unroll 2
    for (int k = 0; k < K; ++k) {
        const float xk = xs[k * 64 + lane];
        const float* __restrict__ wrow = W + (size_t)k * WIDTH + colbase;
#pragma unroll
        for (int o = 0; o < 32; ++o) acc[o] = fmaf(xk, wrow[o], acc[o]);
    }

#pragma unroll
    for (int o = 0; o < 32; ++o) {
        float v = acc[o];
        if (DOELU) v = elu1(v);
        outT[(size_t)(colbase + o) * N_NODES + row] = v;
    }
}

// ---------------------------------------------------------------------------
// Final projection from transposed activations.
// ---------------------------------------------------------------------------
template <int ODIM, bool ADDX>
__global__ __launch_bounds__(256) void final_t(
        const float* __restrict__ actT,   // [126][N]
        const float* __restrict__ Wf,     // [126][ODIM] natural layout
        const float* __restrict__ bf,
        const float* __restrict__ xin,
        float* __restrict__ outp) {
    const int row = blockIdx.x * 256 + threadIdx.x;
    float acc[ODIM];
#pragma unroll
    for (int o = 0; o < ODIM; ++o) acc[o] = bf[o];
#pragma unroll 2
    for (int k = 0; k < WIDTH; ++k) {
        const float a = actT[(size_t)k * N_NODES + row];
#pragma unroll
        for (int o = 0; o < ODIM; ++o) acc[o] = fmaf(a, Wf[k * ODIM + o], acc[o]);
    }
#pragma unroll
    for (int o = 0; o < ODIM; ++o) {
        float v = acc[o];
        if (ADDX) v += xin[(size_t)row * D_IN + 1 + o];
        outp[(size_t)row * ODIM + o] = v;
    }
}

// ---------------------------------------------------------------------------
extern "C" void kernel_launch(void* const* d_in, const int* in_sizes, int n_in,
                              void* d_out, int out_size, void* d_ws, size_t ws_size,
                              hipStream_t stream) {
    (void)in_sizes; (void)n_in; (void)out_size;

    const float* x   = (const float*)d_in[0];
    const float* cWs = (const float*)d_in[1];
    const float* cbs = (const float*)d_in[2];
    const float* cWh = (const float*)d_in[3];
    const float* cbh = (const float*)d_in[4];
    const float* cWo = (const float*)d_in[5];
    const float* cbo = (const float*)d_in[6];
    const float* hW0[3] = {(const float*)d_in[7],  (const float*)d_in[13], (const float*)d_in[19]};
    const float* hb0[3] = {(const float*)d_in[8],  (const float*)d_in[14], (const float*)d_in[20]};
    const float* hWh[3] = {(const float*)d_in[9],  (const float*)d_in[15], (const float*)d_in[21]};
    const float* hbh[3] = {(const float*)d_in[10], (const float*)d_in[16], (const float*)d_in[22]};
    const float* hWf[3] = {(const float*)d_in[11], (const float*)d_in[17], (const float*)d_in[23]};
    const float* hbf[3] = {(const float*)d_in[12], (const float*)d_in[18], (const float*)d_in[24]};
    float* outp = (float*)d_out;
    float* ws = (float*)d_ws;

    // workspace layout (floats)
    const size_t OFF_S   = 0;
    const size_t OFF_H   = OFF_S   + (size_t)N_NODES * 4;
    const size_t OFF_E1  = OFF_H   + (size_t)N_NODES * HPAD;
    const size_t OFF_E2T = OFF_E1  + (size_t)N_NODES * EPAD;
    const size_t OFF_AA  = OFF_E2T + (size_t)EMB * N_NODES;
    const size_t OFF_AB  = OFF_AA  + (size_t)WIDTH * N_NODES;
    const size_t WS_END  = OFF_AB  + (size_t)WIDTH * N_NODES;
    if (ws_size < WS_END * sizeof(float)) return;

    float* s_buf  = ws + OFF_S;
    float* h_buf  = ws + OFF_H;
    float* emb1   = ws + OFF_E1;
    float* emb2T  = ws + OFF_E2T;
    float* act_a  = ws + OFF_AA;
    float* act_b  = ws + OFF_AB;
    // knn scratch aliases act_a (convs finish before heads start)
    float* knnd   = act_a;                                  // 524288 floats
    int*   knnj   = (int*)(act_a + (size_t)N_NODES * 8);    // 524288 ints
    int*   flagp  = (int*)(act_a + (size_t)N_NODES * 16);   // 65536 ints

    // ---- GravNet conv 1 (emb = x, row-major out) ----
    sh_kernel<<<256, 256, 0, stream>>>(x, D_IN, cWs, cbs, cWh, cbh, s_buf, h_buf);
    grav_scan<<<2048, 256, 0, stream>>>(s_buf, knnd, knnj, flagp);
    grav_fix<<<128, 256, 0, stream>>>(s_buf, knnd, knnj, flagp);
    grav_gather<34, false><<<1024, 256, 0, stream>>>(x, h_buf, knnd, knnj, cWo, cbo, emb1);

    // ---- GravNet conv 2 (transposed out for heads) ----
    sh_kernel<<<256, 256, 0, stream>>>(emb1, EPAD, cWs + EMB * S_DIM, cbs + S_DIM,
                                       cWh + EMB * P_DIM, cbh + P_DIM, s_buf, h_buf);
    grav_scan<<<2048, 256, 0, stream>>>(s_buf, knnd, knnj, flagp);
    grav_fix<<<128, 256, 0, stream>>>(s_buf, knnd, knnj, flagp);
    grav_gather<36, true><<<1024, 256, 0, stream>>>(emb1, h_buf, knnd, knnj,
                                                    cWo + CONCAT * EMB, cbo + EMB, emb2T);

    // ---- heads ----
    const size_t ooff[3] = {0, (size_t)N_NODES * 8, (size_t)N_NODES * 12};
    for (int hd = 0; hd < 3; ++hd) {
        mlp_t<EMB, true><<<1024, 256, 0, stream>>>(emb2T, hW0[hd], hb0[hd], act_a);
        mlp_t<WIDTH, true><<<1024, 256, 0, stream>>>(act_a, hWh[hd], hbh[hd], act_b);
        mlp_t<WIDTH, true><<<1024, 256, 0, stream>>>(act_b, hWh[hd] + WIDTH * WIDTH,
                                                     hbh[hd] + WIDTH, act_a);
        if (hd == 0)
            final_t<8, false><<<256, 256, 0, stream>>>(act_a, hWf[hd], hbf[hd], x, outp + ooff[hd]);
        else if (hd == 1)
            final_t<4, true><<<256, 256, 0, stream>>>(act_a, hWf[hd], hbf[hd], x, outp + ooff[hd]);
        else
            final_t<1, false><<<256, 256, 0, stream>>>(act_a, hWf[hd], hbf[hd], x, outp + ooff[hd]);
    }
}

// Round 7
// 1068.806 us; speedup vs baseline: 2.9401x; 2.9401x over previous
//
#include <hip/hip_runtime.h>
#include <math.h>

#define N_NODES 65536
#define NPG     4096
#define D_IN    34
#define EMB     34
#define S_DIM   4
#define P_DIM   22
#define CONCAT  78      // EMB + 2*P_DIM
#define WIDTH   126
#define KNN     8
#define HPAD    24      // padded h row (22 -> 24)
#define EPAD    36      // padded emb row (34 -> 36)
#define TILE    1024    // j-tile staged in LDS
#define NSPLIT  16      // lanes per node
#define FBIG    3.4e38f

__device__ __forceinline__ float elu1(float v) {
    return v > 0.f ? v : expm1f(v);
}

__device__ __forceinline__ bool lexlt(float da, int ja, float db, int jb) {
    return (da < db) || (da == db && ja < jb);
}

// branchless insert of (dd,jj) into sorted-desc depth-4 (slot 0 = worst kept).
// ties keep resident => lex-correct because j scans ascending per lane.
__device__ __forceinline__ void ins4(float (&d)[4], int (&ix)[4], float dd, int jj) {
    const bool s0 = dd < d[0];
    d[0] = s0 ? dd : d[0]; ix[0] = s0 ? jj : ix[0];
#pragma unroll
    for (int r = 0; r < 3; ++r) {
        const bool s = d[r] < d[r + 1];
        const float a = s ? d[r + 1] : d[r], b = s ? d[r] : d[r + 1];
        const int   x = s ? ix[r + 1] : ix[r], y = s ? ix[r] : ix[r + 1];
        d[r] = a; d[r + 1] = b; ix[r] = x; ix[r + 1] = y;
    }
}

// branchless insert into sorted-desc depth-8 (fixup path; exact for 16-way split)
__device__ __forceinline__ void ins8(float (&d)[8], int (&ix)[8], float dd, int jj) {
    const bool s0 = dd < d[0];
    d[0] = s0 ? dd : d[0]; ix[0] = s0 ? jj : ix[0];
#pragma unroll
    for (int r = 0; r < 7; ++r) {
        const bool s = d[r] < d[r + 1];
        const float a = s ? d[r + 1] : d[r], b = s ? d[r] : d[r + 1];
        const int   x = s ? ix[r + 1] : ix[r], y = s ? ix[r] : ix[r + 1];
        d[r] = a; d[r + 1] = b; ix[r] = x; ix[r + 1] = y;
    }
}

// bitonic cleaner: sort a bitonic 8-seq desc by lex (d,j)
__device__ __forceinline__ void clean8(float (&md)[8], int (&mj)[8]) {
#define CASL(i, k) { const bool sw = lexlt(md[i], mj[i], md[k], mj[k]); \
    const float a = sw ? md[k] : md[i], b = sw ? md[i] : md[k]; \
    const int   x = sw ? mj[k] : mj[i], y = sw ? mj[i] : mj[k]; \
    md[i] = a; md[k] = b; mj[i] = x; mj[k] = y; }
    CASL(0,4) CASL(1,5) CASL(2,6) CASL(3,7)
    CASL(0,2) CASL(1,3) CASL(4,6) CASL(5,7)
    CASL(0,1) CASL(2,3) CASL(4,5) CASL(6,7)
#undef CASL
}

// keep 8 lex-smallest of mine(sorted desc) + xor-m partner's, re-sorted desc
__device__ __forceinline__ void merge8(float (&md)[8], int (&mj)[8], int m) {
    float pd[8]; int pj[8];
#pragma unroll
    for (int i = 0; i < 8; ++i) { pd[i] = __shfl_xor(md[i], m); pj[i] = __shfl_xor(mj[i], m); }
#pragma unroll
    for (int i = 0; i < 8; ++i) {
        const bool lt = lexlt(md[i], mj[i], pd[7 - i], pj[7 - i]);
        const float nd = lt ? md[i] : pd[7 - i];
        const int   nj = lt ? mj[i] : pj[7 - i];
        md[i] = nd; mj[i] = nj;
    }
    clean8(md, mj);
}

// ---------------------------------------------------------------------------
// s = emb @ Ws + bs   [N,4];   h = emb @ Wh + bh   [N,22] (stored padded to 24)
// Also zeroes the flagged-node counter (runs right before each grav_scan).
// ---------------------------------------------------------------------------
__global__ __launch_bounds__(256) void sh_kernel(
        const float* __restrict__ emb, int eld,
        const float* __restrict__ Ws, const float* __restrict__ bs,
        const float* __restrict__ Wh, const float* __restrict__ bh,
        float* __restrict__ s_out, float* __restrict__ h_out,
        int* __restrict__ fcnt) {
    if (blockIdx.x == 0 && threadIdx.x == 0) fcnt[0] = 0;

    __shared__ float lWs[EMB * S_DIM];
    __shared__ float lWh[EMB * P_DIM];
    __shared__ float lbs[S_DIM];
    __shared__ float lbh[P_DIM];
    for (int t = threadIdx.x; t < EMB * S_DIM; t += 256) lWs[t] = Ws[t];
    for (int t = threadIdx.x; t < EMB * P_DIM; t += 256) lWh[t] = Wh[t];
    if (threadIdx.x < S_DIM) lbs[threadIdx.x] = bs[threadIdx.x];
    if (threadIdx.x < P_DIM) lbh[threadIdx.x] = bh[threadIdx.x];
    __syncthreads();

    const int n = blockIdx.x * 256 + threadIdx.x;
    const float* __restrict__ row = emb + (size_t)n * eld;
    float e[EMB];
#pragma unroll
    for (int r = 0; r < EMB; ++r) e[r] = row[r];

    float s[S_DIM], h[P_DIM];
#pragma unroll
    for (int c = 0; c < S_DIM; ++c) s[c] = lbs[c];
#pragma unroll
    for (int c = 0; c < P_DIM; ++c) h[c] = lbh[c];
#pragma unroll
    for (int r = 0; r < EMB; ++r) {
        const float er = e[r];
#pragma unroll
        for (int c = 0; c < S_DIM; ++c) s[c] = fmaf(er, lWs[r * S_DIM + c], s[c]);
#pragma unroll
        for (int c = 0; c < P_DIM; ++c) h[c] = fmaf(er, lWh[r * P_DIM + c], h[c]);
    }
    ((float4*)s_out)[n] = make_float4(s[0], s[1], s[2], s[3]);
    float* __restrict__ hr = h_out + (size_t)n * HPAD;
#pragma unroll
    for (int c = 0; c < P_DIM; ++c) hr[c] = h[c];
}

// ---------------------------------------------------------------------------
// kNN scan: 16 lanes/node (j = ql mod 16), 2 nodes/thread share each sj read,
// branchless depth-4 lists, exact lex merge, soundness flag -> compacted
// worklist append. grid = 2048, block = 256.
// ---------------------------------------------------------------------------
__global__ __launch_bounds__(256, 4) void grav_scan(
        const float* __restrict__ s_buf,
        float* __restrict__ knnd, int* __restrict__ knnj,
        int* __restrict__ fcnt, int* __restrict__ flist) {
    __shared__ float4 sl[TILE];           // 16 KB j-tile

    const int g     = blockIdx.x >> 7;
    const int chunk = blockIdx.x & 127;
    const int gbase = g * NPG;
    const int tid   = threadIdx.x;
    const int ql    = tid & 15;
    const int grp   = tid >> 4;
    const int nA    = gbase + chunk * 32 + grp * 2;
    const int nB    = nA + 1;

    const float4* __restrict__ sg = (const float4*)s_buf + gbase;
    float4 pre[4];
#pragma unroll
    for (int i = 0; i < 4; ++i) pre[i] = sg[tid + 256 * i];
    const float4 siA = ((const float4*)s_buf)[nA];
    const float4 siB = ((const float4*)s_buf)[nB];

    float dA[4], dB[4]; int jA[4], jB[4];
#pragma unroll
    for (int r = 0; r < 4; ++r) { dA[r] = FBIG; jA[r] = 0; dB[r] = FBIG; jB[r] = 0; }

#pragma unroll
    for (int i = 0; i < 4; ++i) sl[tid + 256 * i] = pre[i];
    __syncthreads();

    for (int t = 0; t < NPG / TILE; ++t) {
        if (t < NPG / TILE - 1) {
#pragma unroll
            for (int i = 0; i < 4; ++i)
                pre[i] = sg[(t + 1) * TILE + tid + 256 * i];
        }
        const int jb = t * TILE + ql;
#pragma unroll 4
        for (int k = 0; k < TILE / NSPLIT; ++k) {
            const float4 sj = sl[NSPLIT * k + ql];  // 16 distinct b128: conflict-free
            const int jj = jb + NSPLIT * k;
            {
                const float dx = siA.x - sj.x, dy = siA.y - sj.y;
                const float dz = siA.z - sj.z, dw = siA.w - sj.w;
                const float d2 = fmaf(dx, dx, fmaf(dy, dy, fmaf(dz, dz, dw * dw)));
                ins4(dA, jA, d2, jj);
            }
            {
                const float dx = siB.x - sj.x, dy = siB.y - sj.y;
                const float dz = siB.z - sj.z, dw = siB.w - sj.w;
                const float d2 = fmaf(dx, dx, fmaf(dy, dy, fmaf(dz, dz, dw * dw)));
                ins4(dB, jB, d2, jj);
            }
        }
        if (t < NPG / TILE - 1) {
            __syncthreads();
#pragma unroll
            for (int i = 0; i < 4; ++i) sl[tid + 256 * i] = pre[i];
            __syncthreads();
        }
    }

    const int lane = tid & 63;

    // ---- node A: exact merge of 16 depth-4 lists ----
    {
        float md[8]; int mj[8];
        float pd3 = __shfl_xor(dA[3], 1), pd2 = __shfl_xor(dA[2], 1);
        float pd1 = __shfl_xor(dA[1], 1), pd0 = __shfl_xor(dA[0], 1);
        int   pj3 = __shfl_xor(jA[3], 1), pj2 = __shfl_xor(jA[2], 1);
        int   pj1 = __shfl_xor(jA[1], 1), pj0 = __shfl_xor(jA[0], 1);
        md[0] = dA[0]; md[1] = dA[1]; md[2] = dA[2]; md[3] = dA[3];
        mj[0] = jA[0]; mj[1] = jA[1]; mj[2] = jA[2]; mj[3] = jA[3];
        md[4] = pd3; md[5] = pd2; md[6] = pd1; md[7] = pd0;
        mj[4] = pj3; mj[5] = pj2; mj[6] = pj1; mj[7] = pj0;
        clean8(md, mj);                       // desc+asc bitonic -> sorted desc
        merge8(md, mj, 2);
        merge8(md, mj, 4);
        merge8(md, mj, 8);

        const bool lost = !lexlt(md[0], mj[0], dA[0], jA[0]);
        const unsigned long long bal = __ballot(lost);
        const bool flag = (((bal >> (lane & 48)) & 0xFFFFull) != 0ull);

        float ds = md[0]; int js = mj[0];
#pragma unroll
        for (int r = 1; r < 8; ++r) {
            const bool p = (ql == r);
            ds = p ? md[r] : ds; js = p ? mj[r] : js;
        }
        if (ql < 8) {
            knnd[(size_t)nA * 8 + ql] = ds;
            knnj[(size_t)nA * 8 + ql] = js;
        }
        if (ql == 0 && flag) {
            const int slot = atomicAdd(fcnt, 1);
            flist[slot] = nA;
        }
    }

    // ---- node B ----
    {
        float md[8]; int mj[8];
        float pd3 = __shfl_xor(dB[3], 1), pd2 = __shfl_xor(dB[2], 1);
        float pd1 = __shfl_xor(dB[1], 1), pd0 = __shfl_xor(dB[0], 1);
        int   pj3 = __shfl_xor(jB[3], 1), pj2 = __shfl_xor(jB[2], 1);
        int   pj1 = __shfl_xor(jB[1], 1), pj0 = __shfl_xor(jB[0], 1);
        md[0] = dB[0]; md[1] = dB[1]; md[2] = dB[2]; md[3] = dB[3];
        mj[0] = jB[0]; mj[1] = jB[1]; mj[2] = jB[2]; mj[3] = jB[3];
        md[4] = pd3; md[5] = pd2; md[6] = pd1; md[7] = pd0;
        mj[4] = pj3; mj[5] = pj2; mj[6] = pj1; mj[7] = pj0;
        clean8(md, mj);
        merge8(md, mj, 2);
        merge8(md, mj, 4);
        merge8(md, mj, 8);

        const bool lost = !lexlt(md[0], mj[0], dB[0], jB[0]);
        const unsigned long long bal = __ballot(lost);
        const bool flag = (((bal >> (lane & 48)) & 0xFFFFull) != 0ull);

        float ds = md[0]; int js = mj[0];
#pragma unroll
        for (int r = 1; r < 8; ++r) {
            const bool p = (ql == r);
            ds = p ? md[r] : ds; js = p ? mj[r] : js;
        }
        if (ql < 8) {
            knnd[(size_t)nB * 8 + ql] = ds;
            knnj[(size_t)nB * 8 + ql] = js;
        }
        if (ql == 0 && flag) {
            const int slot = atomicAdd(fcnt, 1);
            flist[slot] = nB;
        }
    }
}

// ---------------------------------------------------------------------------
// Fixup: exact rescan of the compacted flagged-node list. One 16-lane group
// per node, grid-stride over the list -> all rescans run concurrently.
// grid = 256 blocks x 256 thr = 4096 groups.
// ---------------------------------------------------------------------------
__global__ __launch_bounds__(256, 4) void grav_fix(
        const float* __restrict__ s_buf,
        float* __restrict__ knnd, int* __restrict__ knnj,
        const int* __restrict__ fcnt, const int* __restrict__ flist) {
    const int cnt = fcnt[0];
    const int ql  = threadIdx.x & 15;
    const int ngroups = gridDim.x * 16;

    for (int idx = blockIdx.x * 16 + (threadIdx.x >> 4); idx < cnt; idx += ngroups) {
        const int node = flist[idx];
        const int gbase = node & ~(NPG - 1);
        const float4 si = ((const float4*)s_buf)[node];
        const float4* __restrict__ sg = (const float4*)s_buf + gbase;

        float fd[8]; int fj[8];
#pragma unroll
        for (int r = 0; r < 8; ++r) { fd[r] = FBIG; fj[r] = 0; }
#pragma unroll 4
        for (int k = 0; k < NPG / NSPLIT; ++k) {
            const int j = NSPLIT * k + ql;
            const float4 sj = sg[j];
            const float dx = si.x - sj.x, dy = si.y - sj.y;
            const float dz = si.z - sj.z, dw = si.w - sj.w;
            const float d2 = fmaf(dx, dx, fmaf(dy, dy, fmaf(dz, dz, dw * dw)));
            ins8(fd, fj, d2, j);
        }
        merge8(fd, fj, 1);
        merge8(fd, fj, 2);
        merge8(fd, fj, 4);
        merge8(fd, fj, 8);

        float ds = fd[0]; int js = fj[0];
#pragma unroll
        for (int r = 1; r < 8; ++r) {
            const bool p = (ql == r);
            ds = p ? fd[r] : ds; js = p ? fj[r] : js;
        }
        if (ql < 8) {
            knnd[(size_t)node * 8 + ql] = ds;
            knnj[(size_t)node * 8 + ql] = js;
        }
    }
}

// ---------------------------------------------------------------------------
// Gather + aggregate + fused output GEMM. 64 nodes/block, 4 lanes/node.
// ---------------------------------------------------------------------------
template <int ELD, bool TOUT>
__global__ __launch_bounds__(256, 4) void grav_gather(
        const float* __restrict__ emb_in,
        const float* __restrict__ h_buf,
        const float* __restrict__ knnd, const int* __restrict__ knnj,
        const float* __restrict__ Wo, const float* __restrict__ bo,
        float* __restrict__ out) {
    __shared__ float wot[EMB * 81];       // Wo^T, rows padded 78 -> 81
    __shared__ float bol[EMB];
    __shared__ float cc[64][49];          // per-node mean @0, max @24

    const int tid = threadIdx.x;
    const int q   = tid & 3;
    const int nl  = tid >> 2;
    const int node = blockIdx.x * 64 + nl;
    const int gbase = node & ~(NPG - 1);

    for (int t = tid; t < CONCAT * EMB; t += 256) {
        const int r = t / EMB, c = t % EMB;
        wot[c * 81 + r] = Wo[t];
    }
    if (tid < EMB) bol[tid] = bo[tid];

    const float da = knnd[(size_t)node * 8 + q];
    const float db = knnd[(size_t)node * 8 + 4 + q];
    const int   ja = knnj[(size_t)node * 8 + q];
    const int   jb = knnj[(size_t)node * 8 + 4 + q];
    const float wa = expf(-10.f * da);
    const float wb = expf(-10.f * db);
    const float4* __restrict__ ha = (const float4*)(h_buf + (size_t)(gbase + ja) * HPAD);
    const float4* __restrict__ hb = (const float4*)(h_buf + (size_t)(gbase + jb) * HPAD);

#pragma unroll
    for (int ch = 0; ch < 6; ++ch) {
        const float4 qa = ha[ch], qb = hb[ch];
        float sx = fmaf(wa, qa.x, wb * qb.x), sy = fmaf(wa, qa.y, wb * qb.y);
        float sz = fmaf(wa, qa.z, wb * qb.z), sw = fmaf(wa, qa.w, wb * qb.w);
        float mx = fmaxf(wa * qa.x, wb * qb.x), my = fmaxf(wa * qa.y, wb * qb.y);
        float mz = fmaxf(wa * qa.z, wb * qb.z), mw = fmaxf(wa * qa.w, wb * qb.w);
#pragma unroll
        for (int m = 1; m <= 2; m <<= 1) {
            sx += __shfl_xor(sx, m); sy += __shfl_xor(sy, m);
            sz += __shfl_xor(sz, m); sw += __shfl_xor(sw, m);
            mx = fmaxf(mx, __shfl_xor(mx, m)); my = fmaxf(my, __shfl_xor(my, m));
            mz = fmaxf(mz, __shfl_xor(mz, m)); mw = fmaxf(mw, __shfl_xor(mw, m));
        }
        if (q == (ch & 3)) {
            cc[nl][ch * 4 + 0] = sx * 0.125f; cc[nl][ch * 4 + 1] = sy * 0.125f;
            cc[nl][ch * 4 + 2] = sz * 0.125f; cc[nl][ch * 4 + 3] = sw * 0.125f;
            cc[nl][24 + ch * 4 + 0] = mx; cc[nl][24 + ch * 4 + 1] = my;
            cc[nl][24 + ch * 4 + 2] = mz; cc[nl][24 + ch * 4 + 3] = mw;
        }
    }
    __syncthreads();

    float e[EMB];
    const float* __restrict__ erow = emb_in + (size_t)node * ELD;
    if constexpr (ELD == 34) {
#pragma unroll
        for (int i = 0; i < 17; ++i) {
            const float2 v = ((const float2*)erow)[i];
            e[2 * i] = v.x; e[2 * i + 1] = v.y;
        }
    } else {
#pragma unroll
        for (int i = 0; i < 8; ++i) {
            const float4 v = ((const float4*)erow)[i];
            e[4 * i] = v.x; e[4 * i + 1] = v.y; e[4 * i + 2] = v.z; e[4 * i + 3] = v.w;
        }
        const float2 v = ((const float2*)erow)[16];
        e[32] = v.x; e[33] = v.y;
    }

#pragma unroll
    for (int m = 0; m < 9; ++m) {
        const int c = q + 4 * m;
        if (c < EMB) {
            const float* __restrict__ wr = &wot[c * 81];
            float acc = bol[c];
#pragma unroll
            for (int r = 0; r < EMB; ++r)   acc = fmaf(e[r], wr[r], acc);
#pragma unroll
            for (int p = 0; p < P_DIM; ++p) acc = fmaf(cc[nl][p], wr[34 + p], acc);
#pragma unroll
            for (int p = 0; p < P_DIM; ++p) acc = fmaf(cc[nl][24 + p], wr[56 + p], acc);
            if constexpr (TOUT)
                out[(size_t)c * N_NODES + node] = acc;
            else
                out[(size_t)node * EPAD + c] = acc;
        }
    }
}

// ---------------------------------------------------------------------------
// Hidden MLP layer on transposed activations: outT[c][n] = act(inT @ W + b).
// ---------------------------------------------------------------------------
template <int K, bool DOELU>
__global__ __launch_bounds__(256, 4) void mlp_t(
        const float* __restrict__ inT,    // [K][N]
        const float* __restrict__ W,      // [K][126] natural layout
        const float* __restrict__ b,      // [126]
        float* __restrict__ outT) {       // [126][N]
    __shared__ float xs[K * 64];
    const int rowbase = blockIdx.x * 64;
    for (int t = threadIdx.x; t < K * 64; t += 256) {
        const int k = t >> 6, r = t & 63;
        xs[t] = inT[(size_t)k * N_NODES + rowbase + r];
    }
    __syncthreads();

    int colbase = __builtin_amdgcn_readfirstlane(threadIdx.x >> 6) * 32;
    if (colbase > WIDTH - 32) colbase = WIDTH - 32;   // wave 3: cols 94..125
    const int lane = threadIdx.x & 63;
    const int row  = rowbase + lane;

    float acc[32];
#pragma unroll
    for (int o = 0; o < 32; ++o) acc[o] = b[colbase + o];

#pragma unroll 2
    for (int k = 0; k < K; ++k) {
        const float xk = xs[k * 64 + lane];
        const float* __restrict__ wrow = W + (size_t)k * WIDTH + colbase;
#pragma unroll
        for (int o = 0; o < 32; ++o) acc[o] = fmaf(xk, wrow[o], acc[o]);
    }

#pragma unroll
    for (int o = 0; o < 32; ++o) {
        float v = acc[o];
        if (DOELU) v = elu1(v);
        outT[(size_t)(colbase + o) * N_NODES + row] = v;
    }
}

// ---------------------------------------------------------------------------
// Final projection from transposed activations.
// ---------------------------------------------------------------------------
template <int ODIM, bool ADDX>
__global__ __launch_bounds__(256) void final_t(
        const float* __restrict__ actT,   // [126][N]
        const float* __restrict__ Wf,     // [126][ODIM] natural layout
        const float* __restrict__ bf,
        const float* __restrict__ xin,
        float* __restrict__ outp) {
    const int row = blockIdx.x * 256 + threadIdx.x;
    float acc[ODIM];
#pragma unroll
    for (int o = 0; o < ODIM; ++o) acc[o] = bf[o];
#pragma unroll 2
    for (int k = 0; k < WIDTH; ++k) {
        const float a = actT[(size_t)k * N_NODES + row];
#pragma unroll
        for (int o = 0; o < ODIM; ++o) acc[o] = fmaf(a, Wf[k * ODIM + o], acc[o]);
    }
#pragma unroll
    for (int o = 0; o < ODIM; ++o) {
        float v = acc[o];
        if (ADDX) v += xin[(size_t)row * D_IN + 1 + o];
        outp[(size_t)row * ODIM + o] = v;
    }
}

// ---------------------------------------------------------------------------
extern "C" void kernel_launch(void* const* d_in, const int* in_sizes, int n_in,
                              void* d_out, int out_size, void* d_ws, size_t ws_size,
                              hipStream_t stream) {
    (void)in_sizes; (void)n_in; (void)out_size;

    const float* x   = (const float*)d_in[0];
    const float* cWs = (const float*)d_in[1];
    const float* cbs = (const float*)d_in[2];
    const float* cWh = (const float*)d_in[3];
    const float* cbh = (const float*)d_in[4];
    const float* cWo = (const float*)d_in[5];
    const float* cbo = (const float*)d_in[6];
    const float* hW0[3] = {(const float*)d_in[7],  (const float*)d_in[13], (const float*)d_in[19]};
    const float* hb0[3] = {(const float*)d_in[8],  (const float*)d_in[14], (const float*)d_in[20]};
    const float* hWh[3] = {(const float*)d_in[9],  (const float*)d_in[15], (const float*)d_in[21]};
    const float* hbh[3] = {(const float*)d_in[10], (const float*)d_in[16], (const float*)d_in[22]};
    const float* hWf[3] = {(const float*)d_in[11], (const float*)d_in[17], (const float*)d_in[23]};
    const float* hbf[3] = {(const float*)d_in[12], (const float*)d_in[18], (const float*)d_in[24]};
    float* outp = (float*)d_out;
    float* ws = (float*)d_ws;

    // workspace layout (floats)
    const size_t OFF_S   = 0;
    const size_t OFF_H   = OFF_S   + (size_t)N_NODES * 4;
    const size_t OFF_E1  = OFF_H   + (size_t)N_NODES * HPAD;
    const size_t OFF_E2T = OFF_E1  + (size_t)N_NODES * EPAD;
    const size_t OFF_AA  = OFF_E2T + (size_t)EMB * N_NODES;
    const size_t OFF_AB  = OFF_AA  + (size_t)WIDTH * N_NODES;
    const size_t WS_END  = OFF_AB  + (size_t)WIDTH * N_NODES;
    if (ws_size < WS_END * sizeof(float)) return;

    float* s_buf  = ws + OFF_S;
    float* h_buf  = ws + OFF_H;
    float* emb1   = ws + OFF_E1;
    float* emb2T  = ws + OFF_E2T;
    float* act_a  = ws + OFF_AA;
    float* act_b  = ws + OFF_AB;
    // knn scratch aliases act_a (convs finish before heads start)
    float* knnd   = act_a;                                   // N*8 floats
    int*   knnj   = (int*)(act_a + (size_t)N_NODES * 8);     // N*8 ints
    int*   flist  = (int*)(act_a + (size_t)N_NODES * 16);    // N ints
    int*   fcnt   = (int*)(act_a + (size_t)N_NODES * 17);    // 1 int

    // ---- GravNet conv 1 (emb = x, row-major out) ----
    sh_kernel<<<256, 256, 0, stream>>>(x, D_IN, cWs, cbs, cWh, cbh, s_buf, h_buf, fcnt);
    grav_scan<<<2048, 256, 0, stream>>>(s_buf, knnd, knnj, fcnt, flist);
    grav_fix<<<256, 256, 0, stream>>>(s_buf, knnd, knnj, fcnt, flist);
    grav_gather<34, false><<<1024, 256, 0, stream>>>(x, h_buf, knnd, knnj, cWo, cbo, emb1);

    // ---- GravNet conv 2 (transposed out for heads) ----
    sh_kernel<<<256, 256, 0, stream>>>(emb1, EPAD, cWs + EMB * S_DIM, cbs + S_DIM,
                                       cWh + EMB * P_DIM, cbh + P_DIM, s_buf, h_buf, fcnt);
    grav_scan<<<2048, 256, 0, stream>>>(s_buf, knnd, knnj, fcnt, flist);
    grav_fix<<<256, 256, 0, stream>>>(s_buf, knnd, knnj, fcnt, flist);
    grav_gather<36, true><<<1024, 256, 0, stream>>>(emb1, h_buf, knnd, knnj,
                                                    cWo + CONCAT * EMB, cbo + EMB, emb2T);

    // ---- heads ----
    const size_t ooff[3] = {0, (size_t)N_NODES * 8, (size_t)N_NODES * 12};
    for (int hd = 0; hd < 3; ++hd) {
        mlp_t<EMB, true><<<1024, 256, 0, stream>>>(emb2T, hW0[hd], hb0[hd], act_a);
        mlp_t<WIDTH, true><<<1024, 256, 0, stream>>>(act_a, hWh[hd], hbh[hd], act_b);
        mlp_t<WIDTH, true><<<1024, 256, 0, stream>>>(act_b, hWh[hd] + WIDTH * WIDTH,
                                                     hbh[hd] + WIDTH, act_a);
        if (hd == 0)
            final_t<8, false><<<256, 256, 0, stream>>>(act_a, hWf[hd], hbf[hd], x, outp + ooff[hd]);
        else if (hd == 1)
            final_t<4, true><<<256, 256, 0, stream>>>(act_a, hWf[hd], hbf[hd], x, outp + ooff[hd]);
        else
            final_t<1, false><<<256, 256, 0, stream>>>(act_a, hWf[hd], hbf[hd], x, outp + ooff[hd]);
    }
}

// Round 8
// 994.378 us; speedup vs baseline: 3.1602x; 1.0748x over previous
//
#include <hip/hip_runtime.h>
#include <math.h>

#define N_NODES 65536
#define NPG     4096
#define D_IN    34
#define EMB     34
#define S_DIM   4
#define P_DIM   22
#define CONCAT  78      // EMB + 2*P_DIM
#define WIDTH   126
#define KNN     8
#define HPAD    24      // padded h row (22 -> 24)
#define EPAD    36      // padded emb row (34 -> 36)
#define TILE    1024    // j-tile staged in LDS
#define NSPLIT  16      // lanes per node
#define FBIG    3.4e38f

__device__ __forceinline__ float elu1(float v) {
    return v > 0.f ? v : expm1f(v);
}

__device__ __forceinline__ bool lexlt(float da, int ja, float db, int jb) {
    return (da < db) || (da == db && ja < jb);
}

// branchless insert of (dd,jj) into sorted-desc depth-4 (slot 0 = worst kept).
__device__ __forceinline__ void ins4(float (&d)[4], int (&ix)[4], float dd, int jj) {
    const bool s0 = dd < d[0];
    d[0] = s0 ? dd : d[0]; ix[0] = s0 ? jj : ix[0];
#pragma unroll
    for (int r = 0; r < 3; ++r) {
        const bool s = d[r] < d[r + 1];
        const float a = s ? d[r + 1] : d[r], b = s ? d[r] : d[r + 1];
        const int   x = s ? ix[r + 1] : ix[r], y = s ? ix[r] : ix[r + 1];
        d[r] = a; d[r + 1] = b; ix[r] = x; ix[r + 1] = y;
    }
}

// branchless insert into sorted-desc depth-8 (fixup path; exact for 16-way split)
__device__ __forceinline__ void ins8(float (&d)[8], int (&ix)[8], float dd, int jj) {
    const bool s0 = dd < d[0];
    d[0] = s0 ? dd : d[0]; ix[0] = s0 ? jj : ix[0];
#pragma unroll
    for (int r = 0; r < 7; ++r) {
        const bool s = d[r] < d[r + 1];
        const float a = s ? d[r + 1] : d[r], b = s ? d[r] : d[r + 1];
        const int   x = s ? ix[r + 1] : ix[r], y = s ? ix[r] : ix[r + 1];
        d[r] = a; d[r + 1] = b; ix[r] = x; ix[r + 1] = y;
    }
}

// bitonic cleaner: sort a bitonic 8-seq desc by lex (d,j)
__device__ __forceinline__ void clean8(float (&md)[8], int (&mj)[8]) {
#define CASL(i, k) { const bool sw = lexlt(md[i], mj[i], md[k], mj[k]); \
    const float a = sw ? md[k] : md[i], b = sw ? md[i] : md[k]; \
    const int   x = sw ? mj[k] : mj[i], y = sw ? mj[i] : mj[k]; \
    md[i] = a; md[k] = b; mj[i] = x; mj[k] = y; }
    CASL(0,4) CASL(1,5) CASL(2,6) CASL(3,7)
    CASL(0,2) CASL(1,3) CASL(4,6) CASL(5,7)
    CASL(0,1) CASL(2,3) CASL(4,5) CASL(6,7)
#undef CASL
}

// keep 8 lex-smallest of mine(sorted desc) + xor-m partner's, re-sorted desc
__device__ __forceinline__ void merge8(float (&md)[8], int (&mj)[8], int m) {
    float pd[8]; int pj[8];
#pragma unroll
    for (int i = 0; i < 8; ++i) { pd[i] = __shfl_xor(md[i], m); pj[i] = __shfl_xor(mj[i], m); }
#pragma unroll
    for (int i = 0; i < 8; ++i) {
        const bool lt = lexlt(md[i], mj[i], pd[7 - i], pj[7 - i]);
        const float nd = lt ? md[i] : pd[7 - i];
        const int   nj = lt ? mj[i] : pj[7 - i];
        md[i] = nd; mj[i] = nj;
    }
    clean8(md, mj);
}

// ---------------------------------------------------------------------------
// s = emb @ Ws + bs   [N,4];   h = emb @ Wh + bh   [N,22] (stored padded to 24)
// Also zeroes the flagged-node counter.
// ---------------------------------------------------------------------------
__global__ __launch_bounds__(256) void sh_kernel(
        const float* __restrict__ emb, int eld,
        const float* __restrict__ Ws, const float* __restrict__ bs,
        const float* __restrict__ Wh, const float* __restrict__ bh,
        float* __restrict__ s_out, float* __restrict__ h_out,
        int* __restrict__ fcnt) {
    if (blockIdx.x == 0 && threadIdx.x == 0) fcnt[0] = 0;

    __shared__ float lWs[EMB * S_DIM];
    __shared__ float lWh[EMB * P_DIM];
    __shared__ float lbs[S_DIM];
    __shared__ float lbh[P_DIM];
    for (int t = threadIdx.x; t < EMB * S_DIM; t += 256) lWs[t] = Ws[t];
    for (int t = threadIdx.x; t < EMB * P_DIM; t += 256) lWh[t] = Wh[t];
    if (threadIdx.x < S_DIM) lbs[threadIdx.x] = bs[threadIdx.x];
    if (threadIdx.x < P_DIM) lbh[threadIdx.x] = bh[threadIdx.x];
    __syncthreads();

    const int n = blockIdx.x * 256 + threadIdx.x;
    const float* __restrict__ row = emb + (size_t)n * eld;
    float e[EMB];
#pragma unroll
    for (int r = 0; r < EMB; ++r) e[r] = row[r];

    float s[S_DIM], h[P_DIM];
#pragma unroll
    for (int c = 0; c < S_DIM; ++c) s[c] = lbs[c];
#pragma unroll
    for (int c = 0; c < P_DIM; ++c) h[c] = lbh[c];
#pragma unroll
    for (int r = 0; r < EMB; ++r) {
        const float er = e[r];
#pragma unroll
        for (int c = 0; c < S_DIM; ++c) s[c] = fmaf(er, lWs[r * S_DIM + c], s[c]);
#pragma unroll
        for (int c = 0; c < P_DIM; ++c) h[c] = fmaf(er, lWh[r * P_DIM + c], h[c]);
    }
    ((float4*)s_out)[n] = make_float4(s[0], s[1], s[2], s[3]);
    float* __restrict__ hr = h_out + (size_t)n * HPAD;
#pragma unroll
    for (int c = 0; c < P_DIM; ++c) hr[c] = h[c];
}

// ---------------------------------------------------------------------------
// kNN scan: 16 lanes/node, 2 nodes/thread, depth-4 lists, exact lex merge,
// soundness flag -> compacted worklist. grid = 2048, block = 256.
// ---------------------------------------------------------------------------
__global__ __launch_bounds__(256, 4) void grav_scan(
        const float* __restrict__ s_buf,
        float* __restrict__ knnd, int* __restrict__ knnj,
        int* __restrict__ fcnt, int* __restrict__ flist) {
    __shared__ float4 sl[TILE];           // 16 KB j-tile

    const int g     = blockIdx.x >> 7;
    const int chunk = blockIdx.x & 127;
    const int gbase = g * NPG;
    const int tid   = threadIdx.x;
    const int ql    = tid & 15;
    const int grp   = tid >> 4;
    const int nA    = gbase + chunk * 32 + grp * 2;
    const int nB    = nA + 1;

    const float4* __restrict__ sg = (const float4*)s_buf + gbase;
    float4 pre[4];
#pragma unroll
    for (int i = 0; i < 4; ++i) pre[i] = sg[tid + 256 * i];
    const float4 siA = ((const float4*)s_buf)[nA];
    const float4 siB = ((const float4*)s_buf)[nB];

    float dA[4], dB[4]; int jA[4], jB[4];
#pragma unroll
    for (int r = 0; r < 4; ++r) { dA[r] = FBIG; jA[r] = 0; dB[r] = FBIG; jB[r] = 0; }

#pragma unroll
    for (int i = 0; i < 4; ++i) sl[tid + 256 * i] = pre[i];
    __syncthreads();

    for (int t = 0; t < NPG / TILE; ++t) {
        if (t < NPG / TILE - 1) {
#pragma unroll
            for (int i = 0; i < 4; ++i)
                pre[i] = sg[(t + 1) * TILE + tid + 256 * i];
        }
        const int jb = t * TILE + ql;
#pragma unroll 4
        for (int k = 0; k < TILE / NSPLIT; ++k) {
            const float4 sj = sl[NSPLIT * k + ql];
            const int jj = jb + NSPLIT * k;
            {
                const float dx = siA.x - sj.x, dy = siA.y - sj.y;
                const float dz = siA.z - sj.z, dw = siA.w - sj.w;
                const float d2 = fmaf(dx, dx, fmaf(dy, dy, fmaf(dz, dz, dw * dw)));
                ins4(dA, jA, d2, jj);
            }
            {
                const float dx = siB.x - sj.x, dy = siB.y - sj.y;
                const float dz = siB.z - sj.z, dw = siB.w - sj.w;
                const float d2 = fmaf(dx, dx, fmaf(dy, dy, fmaf(dz, dz, dw * dw)));
                ins4(dB, jB, d2, jj);
            }
        }
        if (t < NPG / TILE - 1) {
            __syncthreads();
#pragma unroll
            for (int i = 0; i < 4; ++i) sl[tid + 256 * i] = pre[i];
            __syncthreads();
        }
    }

    const int lane = tid & 63;

    // ---- node A ----
    {
        float md[8]; int mj[8];
        float pd3 = __shfl_xor(dA[3], 1), pd2 = __shfl_xor(dA[2], 1);
        float pd1 = __shfl_xor(dA[1], 1), pd0 = __shfl_xor(dA[0], 1);
        int   pj3 = __shfl_xor(jA[3], 1), pj2 = __shfl_xor(jA[2], 1);
        int   pj1 = __shfl_xor(jA[1], 1), pj0 = __shfl_xor(jA[0], 1);
        md[0] = dA[0]; md[1] = dA[1]; md[2] = dA[2]; md[3] = dA[3];
        mj[0] = jA[0]; mj[1] = jA[1]; mj[2] = jA[2]; mj[3] = jA[3];
        md[4] = pd3; md[5] = pd2; md[6] = pd1; md[7] = pd0;
        mj[4] = pj3; mj[5] = pj2; mj[6] = pj1; mj[7] = pj0;
        clean8(md, mj);
        merge8(md, mj, 2);
        merge8(md, mj, 4);
        merge8(md, mj, 8);

        const bool lost = !lexlt(md[0], mj[0], dA[0], jA[0]);
        const unsigned long long bal = __ballot(lost);
        const bool flag = (((bal >> (lane & 48)) & 0xFFFFull) != 0ull);

        float ds = md[0]; int js = mj[0];
#pragma unroll
        for (int r = 1; r < 8; ++r) {
            const bool p = (ql == r);
            ds = p ? md[r] : ds; js = p ? mj[r] : js;
        }
        if (ql < 8) {
            knnd[(size_t)nA * 8 + ql] = ds;
            knnj[(size_t)nA * 8 + ql] = js;
        }
        if (ql == 0 && flag) {
            const int slot = atomicAdd(fcnt, 1);
            flist[slot] = nA;
        }
    }

    // ---- node B ----
    {
        float md[8]; int mj[8];
        float pd3 = __shfl_xor(dB[3], 1), pd2 = __shfl_xor(dB[2], 1);
        float pd1 = __shfl_xor(dB[1], 1), pd0 = __shfl_xor(dB[0], 1);
        int   pj3 = __shfl_xor(jB[3], 1), pj2 = __shfl_xor(jB[2], 1);
        int   pj1 = __shfl_xor(jB[1], 1), pj0 = __shfl_xor(jB[0], 1);
        md[0] = dB[0]; md[1] = dB[1]; md[2] = dB[2]; md[3] = dB[3];
        mj[0] = jB[0]; mj[1] = jB[1]; mj[2] = jB[2]; mj[3] = jB[3];
        md[4] = pd3; md[5] = pd2; md[6] = pd1; md[7] = pd0;
        mj[4] = pj3; mj[5] = pj2; mj[6] = pj1; mj[7] = pj0;
        clean8(md, mj);
        merge8(md, mj, 2);
        merge8(md, mj, 4);
        merge8(md, mj, 8);

        const bool lost = !lexlt(md[0], mj[0], dB[0], jB[0]);
        const unsigned long long bal = __ballot(lost);
        const bool flag = (((bal >> (lane & 48)) & 0xFFFFull) != 0ull);

        float ds = md[0]; int js = mj[0];
#pragma unroll
        for (int r = 1; r < 8; ++r) {
            const bool p = (ql == r);
            ds = p ? md[r] : ds; js = p ? mj[r] : js;
        }
        if (ql < 8) {
            knnd[(size_t)nB * 8 + ql] = ds;
            knnj[(size_t)nB * 8 + ql] = js;
        }
        if (ql == 0 && flag) {
            const int slot = atomicAdd(fcnt, 1);
            flist[slot] = nB;
        }
    }
}

// ---------------------------------------------------------------------------
// Fixup: exact rescan of the compacted flagged-node list (grid-strided).
// ---------------------------------------------------------------------------
__global__ __launch_bounds__(256, 4) void grav_fix(
        const float* __restrict__ s_buf,
        float* __restrict__ knnd, int* __restrict__ knnj,
        const int* __restrict__ fcnt, const int* __restrict__ flist) {
    const int cnt = fcnt[0];
    const int ql  = threadIdx.x & 15;
    const int ngroups = gridDim.x * 16;

    for (int idx = blockIdx.x * 16 + (threadIdx.x >> 4); idx < cnt; idx += ngroups) {
        const int node = flist[idx];
        const int gbase = node & ~(NPG - 1);
        const float4 si = ((const float4*)s_buf)[node];
        const float4* __restrict__ sg = (const float4*)s_buf + gbase;

        float fd[8]; int fj[8];
#pragma unroll
        for (int r = 0; r < 8; ++r) { fd[r] = FBIG; fj[r] = 0; }
#pragma unroll 4
        for (int k = 0; k < NPG / NSPLIT; ++k) {
            const int j = NSPLIT * k + ql;
            const float4 sj = sg[j];
            const float dx = si.x - sj.x, dy = si.y - sj.y;
            const float dz = si.z - sj.z, dw = si.w - sj.w;
            const float d2 = fmaf(dx, dx, fmaf(dy, dy, fmaf(dz, dz, dw * dw)));
            ins8(fd, fj, d2, j);
        }
        merge8(fd, fj, 1);
        merge8(fd, fj, 2);
        merge8(fd, fj, 4);
        merge8(fd, fj, 8);

        float ds = fd[0]; int js = fj[0];
#pragma unroll
        for (int r = 1; r < 8; ++r) {
            const bool p = (ql == r);
            ds = p ? fd[r] : ds; js = p ? fj[r] : js;
        }
        if (ql < 8) {
            knnd[(size_t)node * 8 + ql] = ds;
            knnj[(size_t)node * 8 + ql] = js;
        }
    }
}

// ---------------------------------------------------------------------------
// Gather + aggregate + fused output GEMM. 64 nodes/block, 4 lanes/node.
// ---------------------------------------------------------------------------
template <int ELD, bool TOUT>
__global__ __launch_bounds__(256, 4) void grav_gather(
        const float* __restrict__ emb_in,
        const float* __restrict__ h_buf,
        const float* __restrict__ knnd, const int* __restrict__ knnj,
        const float* __restrict__ Wo, const float* __restrict__ bo,
        float* __restrict__ out) {
    __shared__ float wot[EMB * 81];       // Wo^T, rows padded 78 -> 81
    __shared__ float bol[EMB];
    __shared__ float cc[64][49];          // per-node mean @0, max @24

    const int tid = threadIdx.x;
    const int q   = tid & 3;
    const int nl  = tid >> 2;
    const int node = blockIdx.x * 64 + nl;
    const int gbase = node & ~(NPG - 1);

    for (int t = tid; t < CONCAT * EMB; t += 256) {
        const int r = t / EMB, c = t % EMB;
        wot[c * 81 + r] = Wo[t];
    }
    if (tid < EMB) bol[tid] = bo[tid];

    const float da = knnd[(size_t)node * 8 + q];
    const float db = knnd[(size_t)node * 8 + 4 + q];
    const int   ja = knnj[(size_t)node * 8 + q];
    const int   jb = knnj[(size_t)node * 8 + 4 + q];
    const float wa = expf(-10.f * da);
    const float wb = expf(-10.f * db);
    const float4* __restrict__ ha = (const float4*)(h_buf + (size_t)(gbase + ja) * HPAD);
    const float4* __restrict__ hb = (const float4*)(h_buf + (size_t)(gbase + jb) * HPAD);

#pragma unroll
    for (int ch = 0; ch < 6; ++ch) {
        const float4 qa = ha[ch], qb = hb[ch];
        float sx = fmaf(wa, qa.x, wb * qb.x), sy = fmaf(wa, qa.y, wb * qb.y);
        float sz = fmaf(wa, qa.z, wb * qb.z), sw = fmaf(wa, qa.w, wb * qb.w);
        float mx = fmaxf(wa * qa.x, wb * qb.x), my = fmaxf(wa * qa.y, wb * qb.y);
        float mz = fmaxf(wa * qa.z, wb * qb.z), mw = fmaxf(wa * qa.w, wb * qb.w);
#pragma unroll
        for (int m = 1; m <= 2; m <<= 1) {
            sx += __shfl_xor(sx, m); sy += __shfl_xor(sy, m);
            sz += __shfl_xor(sz, m); sw += __shfl_xor(sw, m);
            mx = fmaxf(mx, __shfl_xor(mx, m)); my = fmaxf(my, __shfl_xor(my, m));
            mz = fmaxf(mz, __shfl_xor(mz, m)); mw = fmaxf(mw, __shfl_xor(mw, m));
        }
        if (q == (ch & 3)) {
            cc[nl][ch * 4 + 0] = sx * 0.125f; cc[nl][ch * 4 + 1] = sy * 0.125f;
            cc[nl][ch * 4 + 2] = sz * 0.125f; cc[nl][ch * 4 + 3] = sw * 0.125f;
            cc[nl][24 + ch * 4 + 0] = mx; cc[nl][24 + ch * 4 + 1] = my;
            cc[nl][24 + ch * 4 + 2] = mz; cc[nl][24 + ch * 4 + 3] = mw;
        }
    }
    __syncthreads();

    float e[EMB];
    const float* __restrict__ erow = emb_in + (size_t)node * ELD;
    if constexpr (ELD == 34) {
#pragma unroll
        for (int i = 0; i < 17; ++i) {
            const float2 v = ((const float2*)erow)[i];
            e[2 * i] = v.x; e[2 * i + 1] = v.y;
        }
    } else {
#pragma unroll
        for (int i = 0; i < 8; ++i) {
            const float4 v = ((const float4*)erow)[i];
            e[4 * i] = v.x; e[4 * i + 1] = v.y; e[4 * i + 2] = v.z; e[4 * i + 3] = v.w;
        }
        const float2 v = ((const float2*)erow)[16];
        e[32] = v.x; e[33] = v.y;
    }

#pragma unroll
    for (int m = 0; m < 9; ++m) {
        const int c = q + 4 * m;
        if (c < EMB) {
            const float* __restrict__ wr = &wot[c * 81];
            float acc = bol[c];
#pragma unroll
            for (int r = 0; r < EMB; ++r)   acc = fmaf(e[r], wr[r], acc);
#pragma unroll
            for (int p = 0; p < P_DIM; ++p) acc = fmaf(cc[nl][p], wr[34 + p], acc);
#pragma unroll
            for (int p = 0; p < P_DIM; ++p) acc = fmaf(cc[nl][24 + p], wr[56 + p], acc);
            if constexpr (TOUT)
                out[(size_t)c * N_NODES + node] = acc;
            else
                out[(size_t)node * EPAD + c] = acc;
        }
    }
}

// ---------------------------------------------------------------------------
// Fused 3-head MLP: one kernel, whole per-head MLP in LDS.
// Block = 512 thr (8 waves x 16 cols), 64 rows. head = blockIdx.x % 3.
// L0 (34->126) -> sA; L1 -> sB; L2 -> sA; final projection from sA in-block.
// Weights via wave-uniform reads; Wf staged in LDS.
// ---------------------------------------------------------------------------
__global__ __launch_bounds__(512, 4) void heads_fused(
        const float* __restrict__ emb2T,   // [34][N]
        const float* __restrict__ xin,
        float* __restrict__ outp,
        const float* __restrict__ W0a, const float* __restrict__ b0a,
        const float* __restrict__ Wha, const float* __restrict__ bha,
        const float* __restrict__ Wfa, const float* __restrict__ bfa,
        const float* __restrict__ W0b, const float* __restrict__ b0b,
        const float* __restrict__ Whb, const float* __restrict__ bhb,
        const float* __restrict__ Wfb, const float* __restrict__ bfb,
        const float* __restrict__ W0c, const float* __restrict__ b0c,
        const float* __restrict__ Whc, const float* __restrict__ bhc,
        const float* __restrict__ Wfc, const float* __restrict__ bfc) {
    __shared__ float sI[EMB * 64];        // 8.5 KB input tile [34][64]
    __shared__ float sA[WIDTH * 64];      // 32.25 KB act [126][64]
    __shared__ float sB[WIDTH * 64];      // 32.25 KB act [126][64]
    __shared__ float sWf[WIDTH * 8];      // final weights (<= 126*8)

    const int tid  = threadIdx.x;
    const int head = blockIdx.x % 3;
    const int rowbase = (blockIdx.x / 3) * 64;
    const int lane = tid & 63;            // row within tile
    const int wave = __builtin_amdgcn_readfirstlane(tid >> 6);
    int colbase = wave * 16;
    if (colbase > WIDTH - 16) colbase = WIDTH - 16;   // wave 7: 110..125

    const float* W0 = head == 0 ? W0a : head == 1 ? W0b : W0c;
    const float* b0 = head == 0 ? b0a : head == 1 ? b0b : b0c;
    const float* Wh = head == 0 ? Wha : head == 1 ? Whb : Whc;
    const float* bh = head == 0 ? bha : head == 1 ? bhb : bhc;
    const float* Wf = head == 0 ? Wfa : head == 1 ? Wfb : Wfc;
    const float* bf = head == 0 ? bfa : head == 1 ? bfb : bfc;
    const int odim  = head == 0 ? 8 : head == 1 ? 4 : 1;
    const size_t ooff = head == 0 ? 0
                      : head == 1 ? (size_t)N_NODES * 8 : (size_t)N_NODES * 12;

    // stage input tile + Wf
    for (int t = tid; t < EMB * 64; t += 512) {
        const int k = t >> 6, r = t & 63;
        sI[t] = emb2T[(size_t)k * N_NODES + rowbase + r];
    }
    for (int t = tid; t < WIDTH * odim; t += 512) sWf[t] = Wf[t];
    __syncthreads();

    float acc[16];

    // ---- L0: 34 -> 126 ----
#pragma unroll
    for (int o = 0; o < 16; ++o) acc[o] = b0[colbase + o];
#pragma unroll 2
    for (int k = 0; k < EMB; ++k) {
        const float xk = sI[k * 64 + lane];
        const float* __restrict__ wr = W0 + (size_t)k * WIDTH + colbase;
#pragma unroll
        for (int o = 0; o < 16; ++o) acc[o] = fmaf(xk, wr[o], acc[o]);
    }
#pragma unroll
    for (int o = 0; o < 16; ++o) sA[(colbase + o) * 64 + lane] = elu1(acc[o]);
    __syncthreads();

    // ---- L1: 126 -> 126 ----
#pragma unroll
    for (int o = 0; o < 16; ++o) acc[o] = bh[colbase + o];
#pragma unroll 2
    for (int k = 0; k < WIDTH; ++k) {
        const float xk = sA[k * 64 + lane];
        const float* __restrict__ wr = Wh + (size_t)k * WIDTH + colbase;
#pragma unroll
        for (int o = 0; o < 16; ++o) acc[o] = fmaf(xk, wr[o], acc[o]);
    }
#pragma unroll
    for (int o = 0; o < 16; ++o) sB[(colbase + o) * 64 + lane] = elu1(acc[o]);
    __syncthreads();

    // ---- L2: 126 -> 126 (writes back into sA) ----
#pragma unroll
    for (int o = 0; o < 16; ++o) acc[o] = bh[WIDTH + colbase + o];
#pragma unroll 2
    for (int k = 0; k < WIDTH; ++k) {
        const float xk = sB[k * 64 + lane];
        const float* __restrict__ wr = Wh + (size_t)(WIDTH + k) * WIDTH + colbase;
#pragma unroll
        for (int o = 0; o < 16; ++o) acc[o] = fmaf(xk, wr[o], acc[o]);
    }
    __syncthreads();   // all L2 reads of sB done; sA reads (L1) long done
#pragma unroll
    for (int o = 0; o < 16; ++o) sA[(colbase + o) * 64 + lane] = elu1(acc[o]);
    __syncthreads();

    // ---- final: out[row][o] = sA[.][row] . Wf[.][o] + bf[o] ----
    // wave w handles rows w*8..w*8+7; 8 lanes per row (q = lane&7), k = q+8m.
    const int q    = lane & 7;
    const int rowl = wave * 8 + (lane >> 3);
    const int grow = rowbase + rowl;

    float fa[8];
#pragma unroll
    for (int o = 0; o < 8; ++o) fa[o] = 0.f;
#pragma unroll 2
    for (int m = 0; m < 16; ++m) {
        const int k = q + 8 * m;
        if (k < WIDTH) {
            const float xa = sA[k * 64 + rowl];
#pragma unroll
            for (int o = 0; o < 8; ++o)
                if (o < odim) fa[o] = fmaf(xa, sWf[k * odim + o], fa[o]);
        }
    }
#pragma unroll
    for (int m = 1; m <= 4; m <<= 1) {
#pragma unroll
        for (int o = 0; o < 8; ++o) fa[o] += __shfl_xor(fa[o], m);
    }
    if (q < odim) {
        float v = fa[q] + bf[q];
        if (head == 1) v += xin[(size_t)grow * D_IN + 1 + q];
        outp[ooff + (size_t)grow * odim + q] = v;
    }
}

// ---------------------------------------------------------------------------
extern "C" void kernel_launch(void* const* d_in, const int* in_sizes, int n_in,
                              void* d_out, int out_size, void* d_ws, size_t ws_size,
                              hipStream_t stream) {
    (void)in_sizes; (void)n_in; (void)out_size;

    const float* x   = (const float*)d_in[0];
    const float* cWs = (const float*)d_in[1];
    const float* cbs = (const float*)d_in[2];
    const float* cWh = (const float*)d_in[3];
    const float* cbh = (const float*)d_in[4];
    const float* cWo = (const float*)d_in[5];
    const float* cbo = (const float*)d_in[6];
    const float* hW0[3] = {(const float*)d_in[7],  (const float*)d_in[13], (const float*)d_in[19]};
    const float* hb0[3] = {(const float*)d_in[8],  (const float*)d_in[14], (const float*)d_in[20]};
    const float* hWh[3] = {(const float*)d_in[9],  (const float*)d_in[15], (const float*)d_in[21]};
    const float* hbh[3] = {(const float*)d_in[10], (const float*)d_in[16], (const float*)d_in[22]};
    const float* hWf[3] = {(const float*)d_in[11], (const float*)d_in[17], (const float*)d_in[23]};
    const float* hbf[3] = {(const float*)d_in[12], (const float*)d_in[18], (const float*)d_in[24]};
    float* outp = (float*)d_out;
    float* ws = (float*)d_ws;

    // workspace layout (floats)
    const size_t OFF_S   = 0;
    const size_t OFF_H   = OFF_S   + (size_t)N_NODES * 4;
    const size_t OFF_E1  = OFF_H   + (size_t)N_NODES * HPAD;
    const size_t OFF_E2T = OFF_E1  + (size_t)N_NODES * EPAD;
    const size_t OFF_KS  = OFF_E2T + (size_t)EMB * N_NODES;
    const size_t WS_END  = OFF_KS  + (size_t)N_NODES * 18;
    if (ws_size < WS_END * sizeof(float)) return;

    float* s_buf  = ws + OFF_S;
    float* h_buf  = ws + OFF_H;
    float* emb1   = ws + OFF_E1;
    float* emb2T  = ws + OFF_E2T;
    float* knnd   = ws + OFF_KS;                             // N*8 floats
    int*   knnj   = (int*)(knnd + (size_t)N_NODES * 8);      // N*8 ints
    int*   flist  = (int*)(knnd + (size_t)N_NODES * 16);     // N ints
    int*   fcnt   = (int*)(knnd + (size_t)N_NODES * 17);     // 1 int

    // ---- GravNet conv 1 (emb = x, row-major out) ----
    sh_kernel<<<256, 256, 0, stream>>>(x, D_IN, cWs, cbs, cWh, cbh, s_buf, h_buf, fcnt);
    grav_scan<<<2048, 256, 0, stream>>>(s_buf, knnd, knnj, fcnt, flist);
    grav_fix<<<256, 256, 0, stream>>>(s_buf, knnd, knnj, fcnt, flist);
    grav_gather<34, false><<<1024, 256, 0, stream>>>(x, h_buf, knnd, knnj, cWo, cbo, emb1);

    // ---- GravNet conv 2 (transposed out for heads) ----
    sh_kernel<<<256, 256, 0, stream>>>(emb1, EPAD, cWs + EMB * S_DIM, cbs + S_DIM,
                                       cWh + EMB * P_DIM, cbh + P_DIM, s_buf, h_buf, fcnt);
    grav_scan<<<2048, 256, 0, stream>>>(s_buf, knnd, knnj, fcnt, flist);
    grav_fix<<<256, 256, 0, stream>>>(s_buf, knnd, knnj, fcnt, flist);
    grav_gather<36, true><<<1024, 256, 0, stream>>>(emb1, h_buf, knnd, knnj,
                                                    cWo + CONCAT * EMB, cbo + EMB, emb2T);

    // ---- heads: one fused dispatch for all 3 MLPs ----
    heads_fused<<<3072, 512, 0, stream>>>(
        emb2T, x, outp,
        hW0[0], hb0[0], hWh[0], hbh[0], hWf[0], hbf[0],
        hW0[1], hb0[1], hWh[1], hbh[1], hWf[1], hbf[1],
        hW0[2], hb0[2], hWh[2], hbh[2], hWf[2], hbf[2]);
}